// Round 4
// baseline (549.597 us; speedup 1.0000x reference)
//
#include <hip/hip_runtime.h>
#include <stdint.h>

#define TSEQ 2048
#define NH   16
#define DKH  64
#define DM   1024

typedef __attribute__((ext_vector_type(8))) __bf16 bf16x8;
typedef __attribute__((ext_vector_type(4))) float floatx4;

__device__ __forceinline__ unsigned short f2bf(float f) {
  union { float f; unsigned u; } v; v.f = f;
  return (unsigned short)((v.u + 0x7fffu + ((v.u >> 16) & 1u)) >> 16);
}
__device__ __forceinline__ bf16x8 ld_frag(const unsigned short* p) {
  bf16x8 r; __builtin_memcpy(&r, p, 16); return r;
}
__device__ __forceinline__ void cp16(unsigned short* dst, const unsigned short* src) {
  uint4 t; __builtin_memcpy(&t, src, 16); __builtin_memcpy(dst, &t, 16);
}
// load 4 fp32, convert to 4 bf16, store 8B to LDS
__device__ __forceinline__ void cvt4(unsigned short* dst, const float* src) {
  float4 t; __builtin_memcpy(&t, src, 16);
  unsigned short u[4] = {f2bf(t.x), f2bf(t.y), f2bf(t.z), f2bf(t.w)};
  __builtin_memcpy(dst, u, 8);
}

// ---------------- transpose 1024x1024: fp32 in -> bf16 out, out[n][k]=in[k][n] ----------------
__global__ void wt_transpose(const float* __restrict__ in,
                             unsigned short* __restrict__ out) {
  __shared__ unsigned short tile[32][33];
  int bx = blockIdx.x * 32, by = blockIdx.y * 32;
  int x = threadIdx.x;
  for (int j = threadIdx.y; j < 32; j += 8)
    tile[j][x] = f2bf(in[(size_t)(by + j) * DM + bx + x]);
  __syncthreads();
  for (int j = threadIdx.y; j < 32; j += 8)
    out[(size_t)(bx + j) * DM + by + x] = tile[x][j];
}

// ---------------- GEMM: C[M x 1024] = A * W + bias, WT[n][k] bf16 ----------------
// MODE 0: A fp32, out bf16 [nb,H,T,DKH] (Q,K)
// MODE 1: A fp32, out bf16 [nb,H,DKH,T] (V)
// MODE 2: A bf16 (ctx), out fp32 [m][n]
template<int MODE>
__global__ __launch_bounds__(256, 2) void gemm_proj(
    const void* __restrict__ Araw,
    const unsigned short* __restrict__ WT,
    const float* __restrict__ bias,
    void* __restrict__ outraw) {
  const int LD = 40;
  __shared__ __align__(16) unsigned short Asm[128 * LD];
  __shared__ __align__(16) unsigned short Bsm[128 * LD];
  const int tid = threadIdx.x;
  const int wave = tid >> 6, lane = tid & 63;
  const int quad = lane >> 4, l16 = lane & 15;
  const int wm = wave & 1, wn = wave >> 1;
  const int m0 = blockIdx.y * 128, n0 = blockIdx.x * 128;

  floatx4 acc[4][4];
#pragma unroll
  for (int i = 0; i < 4; i++)
#pragma unroll
    for (int j = 0; j < 4; j++) acc[i][j] = (floatx4){0.f, 0.f, 0.f, 0.f};

  for (int k0 = 0; k0 < DM; k0 += 32) {
    if (MODE == 2) {
      const unsigned short* A16 = (const unsigned short*)Araw;
#pragma unroll
      for (int i = 0; i < 2; i++) {
        int c = tid + 256 * i;
        int row = c >> 2, k8 = (c & 3) * 8;
        cp16(&Asm[row * LD + k8], &A16[(size_t)(m0 + row) * DM + k0 + k8]);
      }
    } else {
      const float* A32 = (const float*)Araw;
#pragma unroll
      for (int i = 0; i < 4; i++) {
        int c = tid + 256 * i;
        int row = c >> 3, f4 = (c & 7) * 4;
        cvt4(&Asm[row * LD + f4], &A32[(size_t)(m0 + row) * DM + k0 + f4]);
      }
    }
#pragma unroll
    for (int i = 0; i < 2; i++) {
      int c = tid + 256 * i;
      int row = c >> 2, k8 = (c & 3) * 8;
      cp16(&Bsm[row * LD + k8], &WT[(size_t)(n0 + row) * DM + k0 + k8]);
    }
    __syncthreads();
    bf16x8 af[4], bfr[4];
#pragma unroll
    for (int mt = 0; mt < 4; mt++)
      af[mt] = ld_frag(&Asm[(wm * 64 + mt * 16 + l16) * LD + quad * 8]);
#pragma unroll
    for (int nt = 0; nt < 4; nt++)
      bfr[nt] = ld_frag(&Bsm[(wn * 64 + nt * 16 + l16) * LD + quad * 8]);
#pragma unroll
    for (int mt = 0; mt < 4; mt++)
#pragma unroll
      for (int nt = 0; nt < 4; nt++)
        acc[mt][nt] = __builtin_amdgcn_mfma_f32_16x16x32_bf16(af[mt], bfr[nt], acc[mt][nt], 0, 0, 0);
    __syncthreads();
  }

#pragma unroll
  for (int nt = 0; nt < 4; nt++) {
    int n = n0 + wn * 64 + nt * 16 + l16;
    float bv = bias[n];
#pragma unroll
    for (int mt = 0; mt < 4; mt++) {
#pragma unroll
      for (int r = 0; r < 4; r++) {
        int m = m0 + wm * 64 + mt * 16 + quad * 4 + r;
        float val = acc[mt][nt][r] + bv;
        if (MODE == 0) {
          int b = m >> 11, t = m & 2047, h = n >> 6, dk = n & 63;
          ((unsigned short*)outraw)[(size_t)(((b * NH + h) * TSEQ) + t) * DKH + dk] = f2bf(val);
        } else if (MODE == 1) {
          int b = m >> 11, t = m & 2047, h = n >> 6, dk = n & 63;
          ((unsigned short*)outraw)[(size_t)(((b * NH + h) * DKH) + dk) * TSEQ + t] = f2bf(val);
        } else {
          ((float*)outraw)[(size_t)m * DM + n] = val;
        }
      }
    }
  }
}

// ---------------- flash attention (all bf16) ----------------
// Q,K: [nb,H,T,DKH]; VT: [nb,H,DKH,T]; ctx: [nb,T,DM]
__global__ __launch_bounds__(256, 2) void flash_attn(
    const unsigned short* __restrict__ Q,
    const unsigned short* __restrict__ K,
    const unsigned short* __restrict__ VT,
    unsigned short* __restrict__ ctx) {
  const int LD = 72;
  __shared__ __align__(16) unsigned short Qsm[128 * LD];
  __shared__ __align__(16) unsigned short Ksm[64 * LD];
  __shared__ __align__(16) unsigned short Vsm[64 * LD];
  __shared__ __align__(16) unsigned short Psm[4][32 * LD];

  const int tid = threadIdx.x;
  const int wave = tid >> 6, lane = tid & 63;
  const int quad = lane >> 4, l16 = lane & 15;
  const int bh = blockIdx.y;
  const int t0 = blockIdx.x * 128;
  const unsigned short* Qg = Q + (size_t)bh * TSEQ * DKH;
  const unsigned short* Kg = K + (size_t)bh * TSEQ * DKH;
  const unsigned short* Vg = VT + (size_t)bh * DKH * TSEQ;

#pragma unroll
  for (int i = 0; i < 4; i++) {
    int c = tid + 256 * i;
    int row = c >> 3, k8 = (c & 7) * 8;
    cp16(&Qsm[row * LD + k8], &Qg[(size_t)(t0 + row) * DKH + k8]);
  }
  __syncthreads();
  bf16x8 qf[2][2];
#pragma unroll
  for (int mt = 0; mt < 2; mt++)
#pragma unroll
    for (int ks = 0; ks < 2; ks++)
      qf[mt][ks] = ld_frag(&Qsm[(wave * 32 + mt * 16 + l16) * LD + ks * 32 + quad * 8]);

  floatx4 O[2][4];
  float mrun[2][4], lrun[2][4];
#pragma unroll
  for (int mt = 0; mt < 2; mt++) {
#pragma unroll
    for (int nt = 0; nt < 4; nt++) O[mt][nt] = (floatx4){0.f, 0.f, 0.f, 0.f};
#pragma unroll
    for (int r = 0; r < 4; r++) { mrun[mt][r] = -1e30f; lrun[mt][r] = 0.f; }
  }
  const float scale = 0.125f;
  unsigned short* Pw = &Psm[wave][0];

  for (int j0 = 0; j0 < TSEQ; j0 += 64) {
#pragma unroll
    for (int i = 0; i < 2; i++) {
      int c = tid + 256 * i;
      int row = c >> 3, k8 = (c & 7) * 8;
      cp16(&Ksm[row * LD + k8], &Kg[(size_t)(j0 + row) * DKH + k8]);
      cp16(&Vsm[row * LD + k8], &Vg[(size_t)row * TSEQ + j0 + k8]);
    }
    __syncthreads();

    bf16x8 kf[4][2];
#pragma unroll
    for (int nt = 0; nt < 4; nt++)
#pragma unroll
      for (int ks = 0; ks < 2; ks++)
        kf[nt][ks] = ld_frag(&Ksm[(nt * 16 + l16) * LD + ks * 32 + quad * 8]);
    floatx4 s[2][4];
#pragma unroll
    for (int mt = 0; mt < 2; mt++)
#pragma unroll
      for (int nt = 0; nt < 4; nt++) {
        floatx4 a = (floatx4){0.f, 0.f, 0.f, 0.f};
        a = __builtin_amdgcn_mfma_f32_16x16x32_bf16(qf[mt][0], kf[nt][0], a, 0, 0, 0);
        a = __builtin_amdgcn_mfma_f32_16x16x32_bf16(qf[mt][1], kf[nt][1], a, 0, 0, 0);
        s[mt][nt] = a;
      }

#pragma unroll
    for (int mt = 0; mt < 2; mt++) {
#pragma unroll
      for (int r = 0; r < 4; r++) {
        float mx = -1e30f;
#pragma unroll
        for (int nt = 0; nt < 4; nt++) mx = fmaxf(mx, s[mt][nt][r]);
        mx *= scale;
#pragma unroll
        for (int off = 1; off < 16; off <<= 1) mx = fmaxf(mx, __shfl_xor(mx, off, 64));
        float mnew = fmaxf(mrun[mt][r], mx);
        float alpha = __expf(mrun[mt][r] - mnew);
        mrun[mt][r] = mnew;
        float rs = 0.f;
#pragma unroll
        for (int nt = 0; nt < 4; nt++) {
          float p = __expf(s[mt][nt][r] * scale - mnew);
          s[mt][nt][r] = p;
          rs += p;
        }
#pragma unroll
        for (int off = 1; off < 16; off <<= 1) rs += __shfl_xor(rs, off, 64);
        lrun[mt][r] = lrun[mt][r] * alpha + rs;
#pragma unroll
        for (int nt = 0; nt < 4; nt++) O[mt][nt][r] *= alpha;
      }
    }

#pragma unroll
    for (int mt = 0; mt < 2; mt++)
#pragma unroll
      for (int nt = 0; nt < 4; nt++)
#pragma unroll
        for (int r = 0; r < 4; r++)
          Pw[(mt * 16 + quad * 4 + r) * LD + nt * 16 + l16] = f2bf(s[mt][nt][r]);
    __syncthreads();

    bf16x8 vf[4][2];
#pragma unroll
    for (int nt = 0; nt < 4; nt++)
#pragma unroll
      for (int ks = 0; ks < 2; ks++)
        vf[nt][ks] = ld_frag(&Vsm[(nt * 16 + l16) * LD + ks * 32 + quad * 8]);
#pragma unroll
    for (int mt = 0; mt < 2; mt++) {
      bf16x8 pf[2];
#pragma unroll
      for (int ks = 0; ks < 2; ks++)
        pf[ks] = ld_frag(&Pw[(mt * 16 + l16) * LD + ks * 32 + quad * 8]);
#pragma unroll
      for (int nt = 0; nt < 4; nt++) {
        O[mt][nt] = __builtin_amdgcn_mfma_f32_16x16x32_bf16(pf[0], vf[nt][0], O[mt][nt], 0, 0, 0);
        O[mt][nt] = __builtin_amdgcn_mfma_f32_16x16x32_bf16(pf[1], vf[nt][1], O[mt][nt], 0, 0, 0);
      }
    }
    __syncthreads();
  }

  int b = bh >> 4, h = bh & 15;
#pragma unroll
  for (int mt = 0; mt < 2; mt++)
#pragma unroll
    for (int r = 0; r < 4; r++) {
      float inv = 1.0f / lrun[mt][r];
      int t = t0 + wave * 32 + mt * 16 + quad * 4 + r;
#pragma unroll
      for (int nt = 0; nt < 4; nt++) {
        int dk = nt * 16 + l16;
        ctx[((size_t)b * TSEQ + t) * DM + h * DKH + dk] = f2bf(O[mt][nt][r] * inv);
      }
    }
}

extern "C" void kernel_launch(void* const* d_in, const int* in_sizes, int n_in,
                              void* d_out, int out_size, void* d_ws, size_t ws_size,
                              hipStream_t stream) {
  const float* q  = (const float*)d_in[0];
  const float* k  = (const float*)d_in[1];
  const float* v  = (const float*)d_in[2];
  const float* Wq = (const float*)d_in[3];
  const float* bq = (const float*)d_in[4];
  const float* Wk = (const float*)d_in[5];
  const float* bk = (const float*)d_in[6];
  const float* Wv = (const float*)d_in[7];
  const float* bv = (const float*)d_in[8];
  const float* Wo = (const float*)d_in[9];
  const float* bo = (const float*)d_in[10];

  const size_t MiB = 1024 * 1024;
  // footprint = 8 MiB (4 bf16 transposed weights) + nb*16 MiB (bf16 QKV+ctx)
  int nb;
  if      (ws_size >= 72 * MiB) nb = 4;
  else if (ws_size >= 40 * MiB) nb = 2;
  else                          nb = 1;
  const int passes = 4 / nb;

  unsigned char* ws = (unsigned char*)d_ws;
  unsigned short* WqT = (unsigned short*)(ws + 0 * MiB);
  unsigned short* WkT = (unsigned short*)(ws + 2 * MiB);
  unsigned short* WvT = (unsigned short*)(ws + 4 * MiB);
  unsigned short* WoT = (unsigned short*)(ws + 6 * MiB);
  const size_t tensorB = (size_t)nb * 4 * MiB;  // nb*2048*1024 bf16
  unsigned short* Qp = (unsigned short*)(ws + 8 * MiB);
  unsigned short* Kp = (unsigned short*)((unsigned char*)Qp + tensorB);
  unsigned short* Vp = (unsigned short*)((unsigned char*)Kp + tensorB);
  unsigned short* Cx = (unsigned short*)((unsigned char*)Vp + tensorB);

  dim3 tb(32, 8), tg(32, 32);
  wt_transpose<<<tg, tb, 0, stream>>>(Wq, WqT);
  wt_transpose<<<tg, tb, 0, stream>>>(Wk, WkT);
  wt_transpose<<<tg, tb, 0, stream>>>(Wv, WvT);
  wt_transpose<<<tg, tb, 0, stream>>>(Wo, WoT);

  const size_t passElems = (size_t)nb * TSEQ * DM;
  for (int p = 0; p < passes; p++) {
    const float* qp = q + (size_t)p * passElems;
    const float* kp = k + (size_t)p * passElems;
    const float* vp = v + (size_t)p * passElems;
    float* outp = (float*)d_out + (size_t)p * passElems;

    dim3 gg(8, nb * 16);
    gemm_proj<0><<<gg, 256, 0, stream>>>(qp, WqT, bq, Qp);
    gemm_proj<0><<<gg, 256, 0, stream>>>(kp, WkT, bk, Kp);
    gemm_proj<1><<<gg, 256, 0, stream>>>(vp, WvT, bv, Vp);

    flash_attn<<<dim3(16, nb * 16), 256, 0, stream>>>(Qp, Kp, Vp, Cx);

    gemm_proj<2><<<gg, 256, 0, stream>>>(Cx, WoT, bo, outp);
  }
}

// Round 5
// 444.053 us; speedup vs baseline: 1.2377x; 1.2377x over previous
//
#include <hip/hip_runtime.h>
#include <hip/hip_bf16.h>
#include <stdint.h>

#define TSEQ 2048
#define NH   16
#define DKH  64
#define DM   1024

typedef __attribute__((ext_vector_type(8))) __bf16 bf16x8;
typedef __attribute__((ext_vector_type(4))) float floatx4;

#if __has_builtin(__builtin_amdgcn_exp2f)
#define EXP2F(x) __builtin_amdgcn_exp2f(x)
#else
#define EXP2F(x) exp2f(x)
#endif

__device__ __forceinline__ unsigned short f2bf(float f) {
  union { float f; unsigned u; } v; v.f = f;
  return (unsigned short)((v.u + 0x7fffu + ((v.u >> 16) & 1u)) >> 16);
}
// pack 2 fp32 -> 2 bf16 in one dword (v_cvt_pk_bf16_f32 on gfx950)
__device__ __forceinline__ unsigned pack2bf(float a, float b) {
  float2 f; f.x = a; f.y = b;
  __hip_bfloat162 h = __float22bfloat162_rn(f);
  unsigned u; __builtin_memcpy(&u, &h, 4); return u;
}
__device__ __forceinline__ bf16x8 ld_frag(const unsigned short* p) {
  bf16x8 r; __builtin_memcpy(&r, p, 16); return r;
}
__device__ __forceinline__ void cp16(unsigned short* dst, const unsigned short* src) {
  uint4 t; __builtin_memcpy(&t, src, 16); __builtin_memcpy(dst, &t, 16);
}
// load 4 fp32, convert to 4 bf16 (packed), store 8B to LDS
__device__ __forceinline__ void cvt4(unsigned short* dst, const float* src) {
  float4 t; __builtin_memcpy(&t, src, 16);
  uint2 u; u.x = pack2bf(t.x, t.y); u.y = pack2bf(t.z, t.w);
  __builtin_memcpy(dst, &u, 8);
}

// ---------------- transpose 1024x1024: fp32 in -> bf16 out, out[n][k]=in[k][n] ----------------
__global__ void wt_transpose(const float* __restrict__ in,
                             unsigned short* __restrict__ out) {
  __shared__ unsigned short tile[32][33];
  int bx = blockIdx.x * 32, by = blockIdx.y * 32;
  int x = threadIdx.x;
  for (int j = threadIdx.y; j < 32; j += 8)
    tile[j][x] = f2bf(in[(size_t)(by + j) * DM + bx + x]);
  __syncthreads();
  for (int j = threadIdx.y; j < 32; j += 8)
    out[(size_t)(bx + j) * DM + by + x] = tile[x][j];
}

// ---------------- GEMM: C[M x 1024] = A * W + bias, WT[n][k] bf16 ----------------
// MODE 0: A fp32, out bf16 [nb,H,T,DKH] (Q,K)
// MODE 1: A fp32, out bf16 [nb,H,DKH,T] (V)
// MODE 2: A bf16 (ctx), out fp32 [m][n]
template<int MODE>
__global__ __launch_bounds__(256, 2) void gemm_proj(
    const void* __restrict__ Araw,
    const unsigned short* __restrict__ WT,
    const float* __restrict__ bias,
    void* __restrict__ outraw) {
  const int LD = 40;
  __shared__ __align__(16) unsigned short Asm[128 * LD];
  __shared__ __align__(16) unsigned short Bsm[128 * LD];
  const int tid = threadIdx.x;
  const int wave = tid >> 6, lane = tid & 63;
  const int quad = lane >> 4, l16 = lane & 15;
  const int wm = wave & 1, wn = wave >> 1;
  const int m0 = blockIdx.y * 128, n0 = blockIdx.x * 128;

  floatx4 acc[4][4];
#pragma unroll
  for (int i = 0; i < 4; i++)
#pragma unroll
    for (int j = 0; j < 4; j++) acc[i][j] = (floatx4){0.f, 0.f, 0.f, 0.f};

  for (int k0 = 0; k0 < DM; k0 += 32) {
    if (MODE == 2) {
      const unsigned short* A16 = (const unsigned short*)Araw;
#pragma unroll
      for (int i = 0; i < 2; i++) {
        int c = tid + 256 * i;
        int row = c >> 2, k8 = (c & 3) * 8;
        cp16(&Asm[row * LD + k8], &A16[(size_t)(m0 + row) * DM + k0 + k8]);
      }
    } else {
      const float* A32 = (const float*)Araw;
#pragma unroll
      for (int i = 0; i < 4; i++) {
        int c = tid + 256 * i;
        int row = c >> 3, f4 = (c & 7) * 4;
        cvt4(&Asm[row * LD + f4], &A32[(size_t)(m0 + row) * DM + k0 + f4]);
      }
    }
#pragma unroll
    for (int i = 0; i < 2; i++) {
      int c = tid + 256 * i;
      int row = c >> 2, k8 = (c & 3) * 8;
      cp16(&Bsm[row * LD + k8], &WT[(size_t)(n0 + row) * DM + k0 + k8]);
    }
    __syncthreads();
    bf16x8 af[4], bfr[4];
#pragma unroll
    for (int mt = 0; mt < 4; mt++)
      af[mt] = ld_frag(&Asm[(wm * 64 + mt * 16 + l16) * LD + quad * 8]);
#pragma unroll
    for (int nt = 0; nt < 4; nt++)
      bfr[nt] = ld_frag(&Bsm[(wn * 64 + nt * 16 + l16) * LD + quad * 8]);
#pragma unroll
    for (int mt = 0; mt < 4; mt++)
#pragma unroll
      for (int nt = 0; nt < 4; nt++)
        acc[mt][nt] = __builtin_amdgcn_mfma_f32_16x16x32_bf16(af[mt], bfr[nt], acc[mt][nt], 0, 0, 0);
    __syncthreads();
  }

#pragma unroll
  for (int nt = 0; nt < 4; nt++) {
    int n = n0 + wn * 64 + nt * 16 + l16;
    float bv = bias[n];
#pragma unroll
    for (int mt = 0; mt < 4; mt++) {
#pragma unroll
      for (int r = 0; r < 4; r++) {
        int m = m0 + wm * 64 + mt * 16 + quad * 4 + r;
        float val = acc[mt][nt][r] + bv;
        if (MODE == 0) {
          int b = m >> 11, t = m & 2047, h = n >> 6, dk = n & 63;
          ((unsigned short*)outraw)[(size_t)(((b * NH + h) * TSEQ) + t) * DKH + dk] = f2bf(val);
        } else if (MODE == 1) {
          int b = m >> 11, t = m & 2047, h = n >> 6, dk = n & 63;
          ((unsigned short*)outraw)[(size_t)(((b * NH + h) * DKH) + dk) * TSEQ + t] = f2bf(val);
        } else {
          ((float*)outraw)[(size_t)m * DM + n] = val;
        }
      }
    }
  }
}

// ---------------- flash attention (S^T scheme, all bf16) ----------------
// Q,K: [nb,H,T,DKH]; VT: [nb,H,DKH,T]; ctx: [nb,T,DM]
__global__ __launch_bounds__(256, 4) void flash_attn(
    const unsigned short* __restrict__ Q,
    const unsigned short* __restrict__ K,
    const unsigned short* __restrict__ VT,
    unsigned short* __restrict__ ctx) {
  const int LD = 72;
  // QP: Q tile [128][64] during fragment load; then reused as per-wave P [32][64]
  __shared__ __align__(16) unsigned short QP[128 * LD];
  __shared__ __align__(16) unsigned short Ksm[64 * LD];
  __shared__ __align__(16) unsigned short Vsm[64 * LD];

  const int tid = threadIdx.x;
  const int wave = tid >> 6, lane = tid & 63;
  const int quad = lane >> 4, l16 = lane & 15;
  const int bh = blockIdx.y;
  const int t0 = blockIdx.x * 128;
  const unsigned short* Qg = Q + (size_t)bh * TSEQ * DKH;
  const unsigned short* Kg = K + (size_t)bh * TSEQ * DKH;
  const unsigned short* Vg = VT + (size_t)bh * DKH * TSEQ;

#pragma unroll
  for (int i = 0; i < 4; i++) {
    int c = tid + 256 * i;
    int row = c >> 3, k8 = (c & 7) * 8;
    cp16(&QP[row * LD + k8], &Qg[(size_t)(t0 + row) * DKH + k8]);
  }
  __syncthreads();
  // Q fragments (B-operand; n=q on l16, k=d on quad*8+j) — each wave reads ONLY
  // its own 32 rows, which are exactly the rows reused below as its P buffer.
  bf16x8 qf[2][2];
#pragma unroll
  for (int qt = 0; qt < 2; qt++)
#pragma unroll
    for (int ks = 0; ks < 2; ks++)
      qf[qt][ks] = ld_frag(&QP[(wave * 32 + qt * 16 + l16) * LD + ks * 32 + quad * 8]);

  unsigned short* Pw = &QP[wave * 32 * LD];

  floatx4 O[2][4];
  float mrun[2], lrun[2];
#pragma unroll
  for (int qt = 0; qt < 2; qt++) {
#pragma unroll
    for (int dt = 0; dt < 4; dt++) O[qt][dt] = (floatx4){0.f, 0.f, 0.f, 0.f};
    mrun[qt] = -1e30f; lrun[qt] = 0.f;
  }
  const float sl = 0.125f * 1.44269504f;  // scale * log2(e)

  for (int j0 = 0; j0 < TSEQ; j0 += 64) {
#pragma unroll
    for (int i = 0; i < 2; i++) {
      int c = tid + 256 * i;
      int row = c >> 3, k8 = (c & 7) * 8;
      cp16(&Ksm[row * LD + k8], &Kg[(size_t)(j0 + row) * DKH + k8]);
      cp16(&Vsm[row * LD + k8], &Vg[(size_t)row * TSEQ + j0 + k8]);
    }
    __syncthreads();

    // S^T = K Q^T : A = K-frag (m=kv), B = Q-frag (n=q)
    bf16x8 kf[4][2];
#pragma unroll
    for (int kt = 0; kt < 4; kt++)
#pragma unroll
      for (int ks = 0; ks < 2; ks++)
        kf[kt][ks] = ld_frag(&Ksm[(kt * 16 + l16) * LD + ks * 32 + quad * 8]);
    floatx4 st[4][2];  // [kt][qt]: row kv=kt*16+quad*4+r, col q=qt*16+l16
#pragma unroll
    for (int kt = 0; kt < 4; kt++)
#pragma unroll
      for (int qt = 0; qt < 2; qt++) {
        floatx4 a = (floatx4){0.f, 0.f, 0.f, 0.f};
        a = __builtin_amdgcn_mfma_f32_16x16x32_bf16(kf[kt][0], qf[qt][0], a, 0, 0, 0);
        a = __builtin_amdgcn_mfma_f32_16x16x32_bf16(kf[kt][1], qf[qt][1], a, 0, 0, 0);
        st[kt][qt] = a;
      }

    // online softmax: per qt, row q=qt*16+l16; kv spread over regs + quads
    float aO[2][4];
#pragma unroll
    for (int qt = 0; qt < 2; qt++) {
      float mx = -3e38f;
#pragma unroll
      for (int kt = 0; kt < 4; kt++)
#pragma unroll
        for (int r = 0; r < 4; r++) mx = fmaxf(mx, st[kt][qt][r]);
      mx = fmaxf(mx, __shfl_xor(mx, 16, 64));
      mx = fmaxf(mx, __shfl_xor(mx, 32, 64));
      mx *= sl;
      float mnew = fmaxf(mrun[qt], mx);
      float alpha = EXP2F(mrun[qt] - mnew);
      mrun[qt] = mnew;
      float rs = 0.f;
#pragma unroll
      for (int kt = 0; kt < 4; kt++) {
        float p0 = EXP2F(st[kt][qt][0] * sl - mnew);
        float p1 = EXP2F(st[kt][qt][1] * sl - mnew);
        float p2 = EXP2F(st[kt][qt][2] * sl - mnew);
        float p3 = EXP2F(st[kt][qt][3] * sl - mnew);
        rs += (p0 + p1) + (p2 + p3);
        uint2 u; u.x = pack2bf(p0, p1); u.y = pack2bf(p2, p3);
        __builtin_memcpy(&Pw[(qt * 16 + l16) * LD + kt * 16 + quad * 4], &u, 8);
      }
      rs += __shfl_xor(rs, 16, 64);
      rs += __shfl_xor(rs, 32, 64);
      lrun[qt] = lrun[qt] * alpha + rs;
      // broadcast alpha to the O-layout rows (q = qt*16 + quad*4 + r)
#pragma unroll
      for (int r = 0; r < 4; r++)
        aO[qt][r] = __shfl(alpha, quad * 20 + r, 64);
    }
    __syncthreads();  // P writes visible (also wave-internal ordering fence)

#pragma unroll
    for (int qt = 0; qt < 2; qt++)
#pragma unroll
      for (int dt = 0; dt < 4; dt++)
#pragma unroll
        for (int r = 0; r < 4; r++) O[qt][dt][r] *= aO[qt][r];

    // O += P V : A = P-frag (m=q), B = V-frag (n=d)
    bf16x8 vf[4][2];
#pragma unroll
    for (int dt = 0; dt < 4; dt++)
#pragma unroll
      for (int ks = 0; ks < 2; ks++)
        vf[dt][ks] = ld_frag(&Vsm[(dt * 16 + l16) * LD + ks * 32 + quad * 8]);
#pragma unroll
    for (int qt = 0; qt < 2; qt++) {
      bf16x8 pf[2];
#pragma unroll
      for (int ks = 0; ks < 2; ks++)
        pf[ks] = ld_frag(&Pw[(qt * 16 + l16) * LD + ks * 32 + quad * 8]);
#pragma unroll
      for (int dt = 0; dt < 4; dt++) {
        O[qt][dt] = __builtin_amdgcn_mfma_f32_16x16x32_bf16(pf[0], vf[dt][0], O[qt][dt], 0, 0, 0);
        O[qt][dt] = __builtin_amdgcn_mfma_f32_16x16x32_bf16(pf[1], vf[dt][1], O[qt][dt], 0, 0, 0);
      }
    }
    __syncthreads();
  }

  int b = bh >> 4, h = bh & 15;
#pragma unroll
  for (int qt = 0; qt < 2; qt++) {
#pragma unroll
    for (int r = 0; r < 4; r++) {
      float linv = 1.0f / __shfl(lrun[qt], quad * 20 + r, 64);
      int t = t0 + wave * 32 + qt * 16 + quad * 4 + r;
#pragma unroll
      for (int dt = 0; dt < 4; dt++) {
        int dk = dt * 16 + l16;
        ctx[((size_t)b * TSEQ + t) * DM + h * DKH + dk] = f2bf(O[qt][dt][r] * linv);
      }
    }
  }
}

extern "C" void kernel_launch(void* const* d_in, const int* in_sizes, int n_in,
                              void* d_out, int out_size, void* d_ws, size_t ws_size,
                              hipStream_t stream) {
  const float* q  = (const float*)d_in[0];
  const float* k  = (const float*)d_in[1];
  const float* v  = (const float*)d_in[2];
  const float* Wq = (const float*)d_in[3];
  const float* bq = (const float*)d_in[4];
  const float* Wk = (const float*)d_in[5];
  const float* bk = (const float*)d_in[6];
  const float* Wv = (const float*)d_in[7];
  const float* bv = (const float*)d_in[8];
  const float* Wo = (const float*)d_in[9];
  const float* bo = (const float*)d_in[10];

  const size_t MiB = 1024 * 1024;
  int nb;
  if      (ws_size >= 72 * MiB) nb = 4;
  else if (ws_size >= 40 * MiB) nb = 2;
  else                          nb = 1;
  const int passes = 4 / nb;

  unsigned char* ws = (unsigned char*)d_ws;
  unsigned short* WqT = (unsigned short*)(ws + 0 * MiB);
  unsigned short* WkT = (unsigned short*)(ws + 2 * MiB);
  unsigned short* WvT = (unsigned short*)(ws + 4 * MiB);
  unsigned short* WoT = (unsigned short*)(ws + 6 * MiB);
  const size_t tensorB = (size_t)nb * 4 * MiB;
  unsigned short* Qp = (unsigned short*)(ws + 8 * MiB);
  unsigned short* Kp = (unsigned short*)((unsigned char*)Qp + tensorB);
  unsigned short* Vp = (unsigned short*)((unsigned char*)Kp + tensorB);
  unsigned short* Cx = (unsigned short*)((unsigned char*)Vp + tensorB);

  dim3 tb(32, 8), tg(32, 32);
  wt_transpose<<<tg, tb, 0, stream>>>(Wq, WqT);
  wt_transpose<<<tg, tb, 0, stream>>>(Wk, WkT);
  wt_transpose<<<tg, tb, 0, stream>>>(Wv, WvT);
  wt_transpose<<<tg, tb, 0, stream>>>(Wo, WoT);

  const size_t passElems = (size_t)nb * TSEQ * DM;
  for (int p = 0; p < passes; p++) {
    const float* qp = q + (size_t)p * passElems;
    const float* kp = k + (size_t)p * passElems;
    const float* vp = v + (size_t)p * passElems;
    float* outp = (float*)d_out + (size_t)p * passElems;

    dim3 gg(8, nb * 16);
    gemm_proj<0><<<gg, 256, 0, stream>>>(qp, WqT, bq, Qp);
    gemm_proj<0><<<gg, 256, 0, stream>>>(kp, WkT, bk, Kp);
    gemm_proj<1><<<gg, 256, 0, stream>>>(vp, WvT, bv, Vp);

    flash_attn<<<dim3(16, nb * 16), 256, 0, stream>>>(Qp, Kp, Vp, Cx);

    gemm_proj<2><<<gg, 256, 0, stream>>>(Cx, WoT, bo, outp);
  }
}

// Round 6
// 435.113 us; speedup vs baseline: 1.2631x; 1.0205x over previous
//
#include <hip/hip_runtime.h>
#include <hip/hip_bf16.h>
#include <stdint.h>

#define TSEQ 2048
#define NH   16
#define DKH  64
#define DM   1024

typedef __attribute__((ext_vector_type(8))) __bf16 bf16x8;
typedef __attribute__((ext_vector_type(4))) float floatx4;
typedef __attribute__((address_space(1))) void gvoid_t;
typedef __attribute__((address_space(3))) void lvoid_t;

#if __has_builtin(__builtin_amdgcn_exp2f)
#define EXP2F(x) __builtin_amdgcn_exp2f(x)
#else
#define EXP2F(x) exp2f(x)
#endif

__device__ __forceinline__ unsigned short f2bf(float f) {
  union { float f; unsigned u; } v; v.f = f;
  return (unsigned short)((v.u + 0x7fffu + ((v.u >> 16) & 1u)) >> 16);
}
__device__ __forceinline__ unsigned pack2bf(float a, float b) {
  float2 f; f.x = a; f.y = b;
  __hip_bfloat162 h = __float22bfloat162_rn(f);
  unsigned u; __builtin_memcpy(&u, &h, 4); return u;
}
__device__ __forceinline__ bf16x8 cvt8(float4 a, float4 b) {
  unsigned u[4] = {pack2bf(a.x, a.y), pack2bf(a.z, a.w), pack2bf(b.x, b.y), pack2bf(b.z, b.w)};
  bf16x8 r; __builtin_memcpy(&r, u, 16); return r;
}
__device__ __forceinline__ bf16x8 ld_frag(const void* p) {
  bf16x8 r; __builtin_memcpy(&r, p, 16); return r;
}
// async global->LDS DMA, 16B/lane; LDS dest = wave-uniform base + lane*16
__device__ __forceinline__ void gl2lds16(const void* g, void* l) {
  __builtin_amdgcn_global_load_lds((gvoid_t*)(uintptr_t)g,
                                   (lvoid_t*)(unsigned)(uintptr_t)l, 16, 0, 0);
}

// ---------------- fused transpose of 4 weights: fp32 in -> bf16 out[n][k] ----------------
__global__ void wt_transpose4(const float* __restrict__ w0, const float* __restrict__ w1,
                              const float* __restrict__ w2, const float* __restrict__ w3,
                              unsigned short* __restrict__ out) {
  __shared__ unsigned short tile[32][33];
  const float* srcs[4] = {w0, w1, w2, w3};
  const float* in = srcs[blockIdx.z];
  unsigned short* o = out + (size_t)blockIdx.z * DM * DM;
  int bx = blockIdx.x * 32, by = blockIdx.y * 32;
  int x = threadIdx.x;
  for (int j = threadIdx.y; j < 32; j += 8)
    tile[j][x] = f2bf(in[(size_t)(by + j) * DM + bx + x]);
  __syncthreads();
  for (int j = threadIdx.y; j < 32; j += 8)
    o[(size_t)(bx + j) * DM + by + x] = tile[x][j];
}

// ---------------- GEMM: C[M x 1024] = A * W + bias, WT[n][k] bf16 ----------------
// MODE 0: A fp32, out bf16 [nb,H,T,DKH] (Q,K)
// MODE 1: A fp32, out bf16 [nb,H,DKH,T] (V)
// MODE 2: A bf16 (ctx), out fp32 [m][n]
// LDS (all staged by global_load_lds, XOR-swizzled, unpadded):
//   A fp32 [128][32]: 16B chunk c at phys c^(row&7)   (MODE<2)
//   A bf16 [128][32]: 16B chunk c at phys c^((row>>1)&3) (MODE 2)
//   B bf16 [128][32]: 16B chunk c at phys c^((row>>1)&3)
template<int MODE>
__global__ __launch_bounds__(256, 3) void gemm_proj(
    const void* __restrict__ Araw,
    const unsigned short* __restrict__ WT,
    const float* __restrict__ bias,
    void* __restrict__ outraw) {
  constexpr int ABYTES = (MODE == 2) ? 8192 : 16384;
  __shared__ __align__(16) unsigned char Asm[ABYTES];
  __shared__ __align__(16) unsigned char Bsm[8192];
  const int tid = threadIdx.x;
  const int wave = tid >> 6, lane = tid & 63;
  const int quad = lane >> 4, l16 = lane & 15;
  const int wm = wave & 1, wn = wave >> 1;
  const int m0 = blockIdx.y * 128, n0 = blockIdx.x * 128;

  // ---- staging descriptors ----
  const float* gA32[4];
  const unsigned short* gA16[2];
  const unsigned short* gB[2];
  char *ldsA[4], *ldsB[2];
  if (MODE != 2) {
    const float* A32 = (const float*)Araw;
#pragma unroll
    for (int it = 0; it < 4; it++) {
      int cl = (wave * 4 + it) * 64 + lane;
      int row = cl >> 3, phys = cl & 7;
      int cG = phys ^ (row & 7);
      gA32[it] = A32 + (size_t)(m0 + row) * DM + cG * 4;
      ldsA[it] = (char*)Asm + (wave * 4 + it) * 1024;
    }
  } else {
    const unsigned short* A16 = (const unsigned short*)Araw;
#pragma unroll
    for (int it = 0; it < 2; it++) {
      int cl = (wave * 2 + it) * 64 + lane;
      int row = cl >> 2, phys = cl & 3;
      int cG = phys ^ ((row >> 1) & 3);
      gA16[it] = A16 + (size_t)(m0 + row) * DM + cG * 8;
      ldsA[it] = (char*)Asm + (wave * 2 + it) * 1024;
    }
  }
#pragma unroll
  for (int it = 0; it < 2; it++) {
    int cl = (wave * 2 + it) * 64 + lane;
    int row = cl >> 2, phys = cl & 3;
    int cG = phys ^ ((row >> 1) & 3);
    gB[it] = WT + (size_t)(n0 + row) * DM + cG * 8;
    ldsB[it] = (char*)Bsm + (wave * 2 + it) * 1024;
  }

  // ---- fragment LDS offsets (bytes) ----
  int offA0[4], offA1[4], offB[4];
#pragma unroll
  for (int mt = 0; mt < 4; mt++) {
    int row = wm * 64 + mt * 16 + l16;
    if (MODE != 2) {
      offA0[mt] = row * 128 + ((2 * quad) ^ (row & 7)) * 16;
      offA1[mt] = row * 128 + ((2 * quad + 1) ^ (row & 7)) * 16;
    } else {
      offA0[mt] = row * 64 + (quad ^ ((row >> 1) & 3)) * 16;
    }
  }
#pragma unroll
  for (int nt = 0; nt < 4; nt++) {
    int row = wn * 64 + nt * 16 + l16;
    offB[nt] = row * 64 + (quad ^ ((row >> 1) & 3)) * 16;
  }

  floatx4 acc[4][4];
#pragma unroll
  for (int i = 0; i < 4; i++)
#pragma unroll
    for (int j = 0; j < 4; j++) acc[i][j] = (floatx4){0.f, 0.f, 0.f, 0.f};

  for (int k0 = 0; k0 < DM; k0 += 32) {
    if (MODE != 2) {
#pragma unroll
      for (int it = 0; it < 4; it++) { gl2lds16(gA32[it], ldsA[it]); gA32[it] += 32; }
    } else {
#pragma unroll
      for (int it = 0; it < 2; it++) { gl2lds16(gA16[it], ldsA[it]); gA16[it] += 32; }
    }
#pragma unroll
    for (int it = 0; it < 2; it++) { gl2lds16(gB[it], ldsB[it]); gB[it] += 32; }
    __syncthreads();

    bf16x8 af[4], bfr[4];
#pragma unroll
    for (int mt = 0; mt < 4; mt++) {
      if (MODE != 2) {
        float4 fa, fb;
        __builtin_memcpy(&fa, Asm + offA0[mt], 16);
        __builtin_memcpy(&fb, Asm + offA1[mt], 16);
        af[mt] = cvt8(fa, fb);
      } else {
        af[mt] = ld_frag(Asm + offA0[mt]);
      }
    }
#pragma unroll
    for (int nt = 0; nt < 4; nt++)
      bfr[nt] = ld_frag(Bsm + offB[nt]);
#pragma unroll
    for (int mt = 0; mt < 4; mt++)
#pragma unroll
      for (int nt = 0; nt < 4; nt++)
        acc[mt][nt] = __builtin_amdgcn_mfma_f32_16x16x32_bf16(af[mt], bfr[nt], acc[mt][nt], 0, 0, 0);
    __syncthreads();
  }

#pragma unroll
  for (int nt = 0; nt < 4; nt++) {
    int n = n0 + wn * 64 + nt * 16 + l16;
    float bv = bias[n];
#pragma unroll
    for (int mt = 0; mt < 4; mt++) {
#pragma unroll
      for (int r = 0; r < 4; r++) {
        int m = m0 + wm * 64 + mt * 16 + quad * 4 + r;
        float val = acc[mt][nt][r] + bv;
        if (MODE == 0) {
          int b = m >> 11, t = m & 2047, h = n >> 6, dk = n & 63;
          ((unsigned short*)outraw)[(size_t)(((b * NH + h) * TSEQ) + t) * DKH + dk] = f2bf(val);
        } else if (MODE == 1) {
          int b = m >> 11, t = m & 2047, h = n >> 6, dk = n & 63;
          ((unsigned short*)outraw)[(size_t)(((b * NH + h) * DKH) + dk) * TSEQ + t] = f2bf(val);
        } else {
          ((float*)outraw)[(size_t)m * DM + n] = val;
        }
      }
    }
  }
}

// ---------------- flash attention (S^T scheme, swizzled LDS + DMA staging) ----------------
// Q,K: [nb,H,T,DKH]; VT: [nb,H,DKH,T]; ctx: [nb,T,DM]
// LDS rows of 128B = 8 chunks of 16B; chunk c of row r at phys c^(r&7).
__global__ __launch_bounds__(256, 4) void flash_attn(
    const unsigned short* __restrict__ Q,
    const unsigned short* __restrict__ K,
    const unsigned short* __restrict__ VT,
    unsigned short* __restrict__ ctx) {
  __shared__ __align__(16) unsigned short QP[128 * 64];  // Q tile, then per-wave P
  __shared__ __align__(16) unsigned short Ksm[64 * 64];
  __shared__ __align__(16) unsigned short Vsm[64 * 64];

  const int tid = threadIdx.x;
  const int wave = tid >> 6, lane = tid & 63;
  const int quad = lane >> 4, l16 = lane & 15;
  const int bh = blockIdx.y;
  const int t0 = blockIdx.x * 128;
  const unsigned short* Qg = Q + (size_t)bh * TSEQ * DKH;
  const unsigned short* Kg = K + (size_t)bh * TSEQ * DKH;
  const unsigned short* Vg = VT + (size_t)bh * DKH * TSEQ;

  // stage Q: 1024 chunks, 4 DMA per wave
#pragma unroll
  for (int it = 0; it < 4; it++) {
    int cl = (wave * 4 + it) * 64 + lane;
    int row = cl >> 3, phys = cl & 7;
    int cG = phys ^ (row & 7);
    gl2lds16(Qg + (size_t)(t0 + row) * DKH + cG * 8, (char*)QP + (wave * 4 + it) * 1024);
  }
  // K/V staging descriptors (advance per k-tile)
  const unsigned short* gK[2];
  const unsigned short* gV[2];
  char *ldsK[2], *ldsV[2];
#pragma unroll
  for (int it = 0; it < 2; it++) {
    int cl = (wave * 2 + it) * 64 + lane;
    int row = cl >> 3, phys = cl & 7;
    int cG = phys ^ (row & 7);
    gK[it] = Kg + (size_t)row * DKH + cG * 8;
    gV[it] = Vg + (size_t)row * TSEQ + cG * 8;
    ldsK[it] = (char*)Ksm + (wave * 2 + it) * 1024;
    ldsV[it] = (char*)Vsm + (wave * 2 + it) * 1024;
  }
  __syncthreads();

  // fragment offsets: chunk index = ks*4+quad; row&7 == l16&7 everywhere below
  const int sw = l16 & 7;
  int foff[2];  // offset within a 16-row group, for ks=0,1
#pragma unroll
  for (int ks = 0; ks < 2; ks++)
    foff[ks] = l16 * 128 + ((ks * 4 + quad) ^ sw) * 16;

  bf16x8 qf[2][2];
#pragma unroll
  for (int qt = 0; qt < 2; qt++)
#pragma unroll
    for (int ks = 0; ks < 2; ks++)
      qf[qt][ks] = ld_frag((char*)QP + (wave * 32 + qt * 16) * 128 + foff[ks]);

  char* Pw = (char*)QP + wave * 4096;  // wave-private 32 rows

  floatx4 O[2][4];
  float mrun[2], lrun[2];
#pragma unroll
  for (int qt = 0; qt < 2; qt++) {
#pragma unroll
    for (int dt = 0; dt < 4; dt++) O[qt][dt] = (floatx4){0.f, 0.f, 0.f, 0.f};
    mrun[qt] = -1e30f; lrun[qt] = 0.f;
  }
  const float sl = 0.125f * 1.44269504f;  // scale * log2(e)

  for (int j0 = 0; j0 < TSEQ; j0 += 64) {
#pragma unroll
    for (int it = 0; it < 2; it++) {
      gl2lds16(gK[it], ldsK[it]); gK[it] += 64 * DKH;
      gl2lds16(gV[it], ldsV[it]); gV[it] += 64;
    }
    __syncthreads();

    // S^T = K Q^T : A = K-frag (m=kv), B = Q-frag (n=q)
    bf16x8 kf[4][2];
#pragma unroll
    for (int kt = 0; kt < 4; kt++)
#pragma unroll
      for (int ks = 0; ks < 2; ks++)
        kf[kt][ks] = ld_frag((char*)Ksm + kt * 16 * 128 + foff[ks]);
    floatx4 st[4][2];
#pragma unroll
    for (int kt = 0; kt < 4; kt++)
#pragma unroll
      for (int qt = 0; qt < 2; qt++) {
        floatx4 a = (floatx4){0.f, 0.f, 0.f, 0.f};
        a = __builtin_amdgcn_mfma_f32_16x16x32_bf16(kf[kt][0], qf[qt][0], a, 0, 0, 0);
        a = __builtin_amdgcn_mfma_f32_16x16x32_bf16(kf[kt][1], qf[qt][1], a, 0, 0, 0);
        st[kt][qt] = a;
      }

    // online softmax (row q = l16 per qt) + P write (swizzled, 8B packed)
    float aO[2][4];
#pragma unroll
    for (int qt = 0; qt < 2; qt++) {
      float mx = -3e38f;
#pragma unroll
      for (int kt = 0; kt < 4; kt++)
#pragma unroll
        for (int r = 0; r < 4; r++) mx = fmaxf(mx, st[kt][qt][r]);
      mx = fmaxf(mx, __shfl_xor(mx, 16, 64));
      mx = fmaxf(mx, __shfl_xor(mx, 32, 64));
      mx *= sl;
      float mnew = fmaxf(mrun[qt], mx);
      float alpha = EXP2F(mrun[qt] - mnew);
      mrun[qt] = mnew;
      float rs = 0.f;
#pragma unroll
      for (int kt = 0; kt < 4; kt++) {
        float p0 = EXP2F(st[kt][qt][0] * sl - mnew);
        float p1 = EXP2F(st[kt][qt][1] * sl - mnew);
        float p2 = EXP2F(st[kt][qt][2] * sl - mnew);
        float p3 = EXP2F(st[kt][qt][3] * sl - mnew);
        rs += (p0 + p1) + (p2 + p3);
        uint2 u; u.x = pack2bf(p0, p1); u.y = pack2bf(p2, p3);
        int physC = (2 * kt + (quad >> 1)) ^ sw;
        __builtin_memcpy(Pw + (qt * 16 + l16) * 128 + physC * 16 + (quad & 1) * 8, &u, 8);
      }
      rs += __shfl_xor(rs, 16, 64);
      rs += __shfl_xor(rs, 32, 64);
      lrun[qt] = lrun[qt] * alpha + rs;
#pragma unroll
      for (int r = 0; r < 4; r++)
        aO[qt][r] = __shfl(alpha, quad * 20 + r, 64);
    }
    // no block barrier: P is wave-private; same-wave DS ops are in-order

#pragma unroll
    for (int qt = 0; qt < 2; qt++)
#pragma unroll
      for (int dt = 0; dt < 4; dt++)
#pragma unroll
        for (int r = 0; r < 4; r++) O[qt][dt][r] *= aO[qt][r];

    // O += P V : A = P-frag (m=q), B = V-frag (n=d)
    bf16x8 vf[4][2];
#pragma unroll
    for (int dt = 0; dt < 4; dt++)
#pragma unroll
      for (int ks = 0; ks < 2; ks++)
        vf[dt][ks] = ld_frag((char*)Vsm + dt * 16 * 128 + foff[ks]);
#pragma unroll
    for (int qt = 0; qt < 2; qt++) {
      bf16x8 pf[2];
#pragma unroll
      for (int ks = 0; ks < 2; ks++)
        pf[ks] = ld_frag(Pw + qt * 16 * 128 + foff[ks]);
#pragma unroll
      for (int dt = 0; dt < 4; dt++) {
        O[qt][dt] = __builtin_amdgcn_mfma_f32_16x16x32_bf16(pf[0], vf[dt][0], O[qt][dt], 0, 0, 0);
        O[qt][dt] = __builtin_amdgcn_mfma_f32_16x16x32_bf16(pf[1], vf[dt][1], O[qt][dt], 0, 0, 0);
      }
    }
    __syncthreads();
  }

  int b = bh >> 4, h = bh & 15;
#pragma unroll
  for (int qt = 0; qt < 2; qt++) {
#pragma unroll
    for (int r = 0; r < 4; r++) {
      float linv = 1.0f / __shfl(lrun[qt], quad * 20 + r, 64);
      int t = t0 + wave * 32 + qt * 16 + quad * 4 + r;
#pragma unroll
      for (int dt = 0; dt < 4; dt++) {
        int dk = dt * 16 + l16;
        ctx[((size_t)b * TSEQ + t) * DM + h * DKH + dk] = f2bf(O[qt][dt][r] * linv);
      }
    }
  }
}

extern "C" void kernel_launch(void* const* d_in, const int* in_sizes, int n_in,
                              void* d_out, int out_size, void* d_ws, size_t ws_size,
                              hipStream_t stream) {
  const float* q  = (const float*)d_in[0];
  const float* k  = (const float*)d_in[1];
  const float* v  = (const float*)d_in[2];
  const float* Wq = (const float*)d_in[3];
  const float* bq = (const float*)d_in[4];
  const float* Wk = (const float*)d_in[5];
  const float* bk = (const float*)d_in[6];
  const float* Wv = (const float*)d_in[7];
  const float* bv = (const float*)d_in[8];
  const float* Wo = (const float*)d_in[9];
  const float* bo = (const float*)d_in[10];

  const size_t MiB = 1024 * 1024;
  int nb;
  if      (ws_size >= 72 * MiB) nb = 4;
  else if (ws_size >= 40 * MiB) nb = 2;
  else                          nb = 1;
  const int passes = 4 / nb;

  unsigned char* ws = (unsigned char*)d_ws;
  unsigned short* WTs = (unsigned short*)ws;  // 4 x 2 MiB: WqT,WkT,WvT,WoT
  unsigned short* WqT = WTs + 0 * DM * DM;
  unsigned short* WkT = WTs + 1 * DM * DM;
  unsigned short* WvT = WTs + 2 * DM * DM;
  unsigned short* WoT = WTs + 3 * DM * DM;
  const size_t tensorB = (size_t)nb * 4 * MiB;
  unsigned short* Qp = (unsigned short*)(ws + 8 * MiB);
  unsigned short* Kp = (unsigned short*)((unsigned char*)Qp + tensorB);
  unsigned short* Vp = (unsigned short*)((unsigned char*)Kp + tensorB);
  unsigned short* Cx = (unsigned short*)((unsigned char*)Vp + tensorB);

  wt_transpose4<<<dim3(32, 32, 4), dim3(32, 8), 0, stream>>>(Wq, Wk, Wv, Wo, WTs);

  const size_t passElems = (size_t)nb * TSEQ * DM;
  for (int p = 0; p < passes; p++) {
    const float* qp = q + (size_t)p * passElems;
    const float* kp = k + (size_t)p * passElems;
    const float* vp = v + (size_t)p * passElems;
    float* outp = (float*)d_out + (size_t)p * passElems;

    dim3 gg(8, nb * 16);
    gemm_proj<0><<<gg, 256, 0, stream>>>(qp, WqT, bq, Qp);
    gemm_proj<0><<<gg, 256, 0, stream>>>(kp, WkT, bk, Kp);
    gemm_proj<1><<<gg, 256, 0, stream>>>(vp, WvT, bv, Vp);

    flash_attn<<<dim3(16, nb * 16), 256, 0, stream>>>(Qp, Kp, Vp, Cx);

    gemm_proj<2><<<gg, 256, 0, stream>>>(Cx, WoT, bo, outp);
  }
}